// Round 12
// baseline (815.731 us; speedup 1.0000x reference)
//
#include <hip/hip_runtime.h>
#include <hip/hip_bf16.h>
#include <hip/hip_cooperative_groups.h>

namespace cg = cooperative_groups;

typedef __hip_bfloat16 bf16;
typedef __attribute__((ext_vector_type(8))) __bf16 bf16x8;
typedef __attribute__((ext_vector_type(4))) float f32x4;

static constexpr int N = 100000;
static constexpr int E = 1600000;
static constexpr int ETOT = E + N;   // self-loops appended after the E edges
static constexpr float SLOPE = 0.2f;

// ---- param table: W1,as1,ad1,b1, W2,as2,ad2,b2, W3,as3,ad3,b3 (fp32 flat) --
__device__ __constant__ int c_poff[12] = {0, 16384, 16512, 16640,
                                          16768, 24960, 25024, 25088,
                                          25152, 26176, 26192, 26208};
static constexpr int PTOT = 26224;
static constexpr int H_POFF[12] = {0, 16384, 16512, 16640, 16768, 24960,
                                   25024, 25088, 25152, 26176, 26192, 26208};

struct Src12 { const void* p[12]; };

__device__ __forceinline__ float bfLo(unsigned u) { return __uint_as_float(u << 16); }
__device__ __forceinline__ float bfHi(unsigned u) { return __uint_as_float(u & 0xFFFF0000u); }

__device__ __forceinline__ void fma8(const uint4 r, float e, float* acc) {
  acc[0] = fmaf(e, bfLo(r.x), acc[0]);
  acc[1] = fmaf(e, bfHi(r.x), acc[1]);
  acc[2] = fmaf(e, bfLo(r.y), acc[2]);
  acc[3] = fmaf(e, bfHi(r.y), acc[3]);
  acc[4] = fmaf(e, bfLo(r.z), acc[4]);
  acc[5] = fmaf(e, bfHi(r.z), acc[5]);
  acc[6] = fmaf(e, bfLo(r.w), acc[6]);
  acc[7] = fmaf(e, bfHi(r.w), acc[7]);
}

__device__ __forceinline__ float edge_ex(float l) {
  l = (l > 0.f) ? l : SLOPE * l;
  return __expf(l);
}

__device__ __forceinline__ void loadEdge(const int* __restrict__ ei32,
                                         const long long* __restrict__ ei64,
                                         int use64, int t, int& s, int& d) {
  if (t >= E) { s = d = t - E; return; }
  if (use64) { s = (int)ei64[t]; d = (int)ei64[E + t]; }
  else       { s = ei32[t];      d = ei32[E + t]; }
}

__device__ __forceinline__ unsigned pk2(float a, float b) {
  bf16 x = __float2bfloat16(a), y = __float2bfloat16(b);
  unsigned short ux = *(unsigned short*)&x, uy = *(unsigned short*)&y;
  return ((unsigned)uy << 16) | ux;
}

// ---- bucket-sort geometry ----
static constexpr int CHUNK = 8192;
static constexpr int NCHK  = (ETOT + CHUNK - 1) / CHUNK;   // 208
static constexpr int NB1   = (N + 511) / 512;              // 196 coarse buckets
static constexpr int M1    = NB1 * NCHK;                   // 40768
static constexpr int SBLK  = (M1 + 255) / 256;             // 160

// ---- flags: flags[0]=edge idx is int64; flags[1]=float tensors are fp32 ---
__global__ __launch_bounds__(256) void detect_kernel(
    const unsigned long long* __restrict__ ei64,
    const unsigned short* __restrict__ w1u16, int* __restrict__ flags) {
  const int t = threadIdx.x;
  __shared__ unsigned long long bl[4];
  __shared__ unsigned long long sb64;
  const int w = t >> 6;
  bool p64 = (t < 64) && (ei64[t] >= (unsigned long long)N);
  unsigned long long b64 = __ballot(p64);
  if (t == 0) sb64 = b64;
  // W1 glorot-bounded (|v|<=0.154) -> bf16 exp field < 126; fp32 low halves
  // are random -> exp>=126 appears within 256 samples w.h.p.
  bool pf = (((w1u16[t] >> 7) & 0xFFu) >= 126u);
  unsigned long long bf_ = __ballot(pf);
  if ((t & 63) == 0) bl[w] = bf_;
  __syncthreads();
  if (t == 0) {
    flags[0] = (sb64 == 0ull) ? 1 : 0;
    flags[1] = ((bl[0] | bl[1] | bl[2] | bl[3]) != 0ull) ? 1 : 0;
  }
}

// ---- K2: phase A (coarse LDS histogram) || param/W converts ---------------
static constexpr int PB_PAR = (PTOT + 255) / 256;  // 103
static constexpr int PB_W1  = 128 * 128 / 256;     // 64
static constexpr int PB_W2  = 128 * 64 / 256;      // 32
static constexpr int PB_W3  = 64 * 16 / 256;       // 4
static constexpr int PB_TOT = NCHK + PB_PAR + PB_W1 + PB_W2 + PB_W3;

__device__ __forceinline__ void conv_w(const void* W, int kd, int dout, int f32,
                                       bf16* __restrict__ wt, int idx) {
  int n = idx / kd, k = idx - n * kd;
  float v = f32 ? ((const float*)W)[k * dout + n]
                : __bfloat162float(((const bf16*)W)[k * dout + n]);
  wt[idx] = __float2bfloat16(v);
}

__global__ __launch_bounds__(256) void prep_kernel(
    const int* __restrict__ ei32, const long long* __restrict__ ei64,
    const int* __restrict__ flags, int* __restrict__ c1,
    Src12 s, float* __restrict__ prm,
    bf16* __restrict__ w1t, bf16* __restrict__ w2t, bf16* __restrict__ w3t) {
  const int b = blockIdx.x, tid = threadIdx.x;
  const int f64 = flags[0], f32 = flags[1];
  if (b < NCHK) {
    __shared__ int h1[NB1];
    if (tid < NB1) h1[tid] = 0;
    __syncthreads();
    const int t0 = b * CHUNK;
#pragma unroll 4
    for (int i = tid; i < CHUNK; i += 256) {
      int t = t0 + i;
      if (t < ETOT) {
        int d = (t >= E) ? (t - E) : (f64 ? (int)ei64[E + t] : ei32[E + t]);
        atomicAdd(&h1[d >> 9], 1);
      }
    }
    __syncthreads();
    if (tid < NB1) c1[tid * NCHK + b] = h1[tid];   // bin-major
  } else if (b < NCHK + PB_PAR) {
    int t = (b - NCHK) * 256 + tid;
    if (t < PTOT) {
      int k = 0;
#pragma unroll
      for (int i = 1; i < 12; ++i)
        if (t >= c_poff[i]) k = i;
      int j = t - c_poff[k];
      prm[t] = f32 ? ((const float*)s.p[k])[j]
                   : __bfloat162float(((const bf16*)s.p[k])[j]);
    }
  } else if (b < NCHK + PB_PAR + PB_W1) {
    conv_w(s.p[0], 128, 128, f32, w1t, (b - NCHK - PB_PAR) * 256 + tid);
  } else if (b < NCHK + PB_PAR + PB_W1 + PB_W2) {
    conv_w(s.p[4], 128, 64, f32, w2t, (b - NCHK - PB_PAR - PB_W1) * 256 + tid);
  } else {
    conv_w(s.p[8], 64, 16, f32, w3t, (b - NCHK - PB_PAR - PB_W1 - PB_W2) * 256 + tid);
  }
}

// ---- 3-phase exclusive scan of c1[0..M1) -> off1 --------------------------
__global__ __launch_bounds__(256) void scanA_kernel(const int* __restrict__ c1,
                                                    int* __restrict__ bsum) {
  __shared__ int red[256];
  const int t = threadIdx.x;
  const int i = blockIdx.x * 256 + t;
  red[t] = (i < M1) ? c1[i] : 0;
  __syncthreads();
#pragma unroll
  for (int off = 128; off > 0; off >>= 1) {
    if (t < off) red[t] += red[t + off];
    __syncthreads();
  }
  if (t == 0) bsum[blockIdx.x] = red[0];
}

__global__ __launch_bounds__(256) void scanB_kernel(const int* __restrict__ bsum,
                                                    int* __restrict__ boff) {
  __shared__ int s[256];
  const int t = threadIdx.x;
  const int v = (t < SBLK) ? bsum[t] : 0;
  s[t] = v;
  __syncthreads();
  for (int off = 1; off < 256; off <<= 1) {
    int u = (t >= off) ? s[t - off] : 0;
    __syncthreads();
    s[t] += u;
    __syncthreads();
  }
  if (t < SBLK) boff[t] = s[t] - v;
}

__global__ __launch_bounds__(256) void scanC_kernel(const int* __restrict__ c1,
                                                    const int* __restrict__ boff,
                                                    int* __restrict__ off1) {
  __shared__ int s[256];
  const int t = threadIdx.x;
  const int i = blockIdx.x * 256 + t;
  const int v = (i < M1) ? c1[i] : 0;
  s[t] = v;
  __syncthreads();
#pragma unroll
  for (int off = 1; off < 256; off <<= 1) {
    int u = (t >= off) ? s[t - off] : 0;
    __syncthreads();
    s[t] += u;
    __syncthreads();
  }
  if (i < M1) off1[i] = boff[blockIdx.x] + s[t] - v;
}

// ---- phase C body: scatter edges into coarse buckets via LDS cursors ------
__device__ __forceinline__ void phaseC_body(int c, const int* __restrict__ ei32,
                                            const long long* __restrict__ ei64,
                                            int f64, const int* __restrict__ off1,
                                            int2* __restrict__ tmp, int* sm) {
  int* cur = sm;                       // NB1 ints
  const int tid = threadIdx.x;
  if (tid < NB1) cur[tid] = off1[tid * NCHK + c];
  __syncthreads();
  const int t0 = c * CHUNK;
#pragma unroll 4
  for (int i = tid; i < CHUNK; i += 256) {
    int t = t0 + i;
    if (t < ETOT) {
      int s, d;
      loadEdge(ei32, ei64, f64, t, s, d);
      int pos = atomicAdd(&cur[d >> 9], 1);
      tmp[pos] = make_int2(d, s);
    }
  }
}

// ---- phase D body: per-bucket fine counting sort -> rowptr + ssrt ---------
__device__ __forceinline__ void phaseD_body(int b, const int* __restrict__ off1,
                                            const int2* __restrict__ tmp,
                                            int* __restrict__ rowptr,
                                            int* __restrict__ ssrt, int* sm) {
  int* h2 = sm;            // 512
  int* e2 = sm + 512;      // 512
  int* cur = sm + 1024;    // 512
  int* ps = sm + 1536;     // 256
  const int t = threadIdx.x;
  const int base = off1[b * NCHK];
  const int end = (b + 1 < NB1) ? off1[(b + 1) * NCHK] : ETOT;
  const int len = end - base;
  h2[2 * t] = 0; h2[2 * t + 1] = 0;
  __syncthreads();
  for (int i = t; i < len; i += 256)
    atomicAdd(&h2[tmp[base + i].x & 511], 1);
  __syncthreads();
  const int s1 = h2[2 * t], s2 = h2[2 * t + 1];
  ps[t] = s1 + s2;
  __syncthreads();
  for (int off = 1; off < 256; off <<= 1) {
    int u = (t >= off) ? ps[t - off] : 0;
    __syncthreads();
    ps[t] += u;
    __syncthreads();
  }
  const int ep = ps[t] - (s1 + s2);
  e2[2 * t] = ep;
  e2[2 * t + 1] = ep + s1;
  cur[2 * t] = ep;
  cur[2 * t + 1] = ep + s1;
  __syncthreads();
#pragma unroll
  for (int k = 0; k < 2; ++k) {
    int f = 2 * t + k;
    int node = (b << 9) + f;
    if (node < N) rowptr[node] = base + e2[f];
  }
  if (b == 0 && t == 0) rowptr[N] = ETOT;
  for (int i = t; i < len; i += 256) {
    int2 e = tmp[base + i];
    int pos = base + atomicAdd(&cur[e.x & 511], 1);
    ssrt[pos] = e.y;
  }
}

// -------- MFMA GEMM body (64 rows x DOUT) + fused al epilogue --------------
// XD: stage A directly from x (fp32/bf16 per flags[1]); BG: B from global.
template <int KD, int DOUT, bool XD, bool BG>
__device__ __forceinline__ void gemm_body(int bb, const void* __restrict__ inv,
                                          const int* __restrict__ flags,
                                          const unsigned short* __restrict__ wt,
                                          bf16* __restrict__ h,
                                          const float* __restrict__ a_s,
                                          const float* __restrict__ a_d,
                                          float* __restrict__ als,
                                          float* __restrict__ ald,
                                          unsigned short* sA, unsigned short* sB) {
  constexpr int SA = KD + 8;
  constexpr int NT = DOUT / 16;      // 8 / 4 / 1
  constexpr int KS = KD / 32;        // 4 / 4 / 2
  const int tid = threadIdx.x;
  const int m0 = bb * 64;
  if (!BG) {
    for (int idx = tid; idx < DOUT * KD / 8; idx += 256) {
      int n = idx / (KD / 8), k8 = idx - n * (KD / 8);
      *(uint4*)(sB + n * SA + k8 * 8) = *(const uint4*)(wt + n * KD + k8 * 8);
    }
  }
  const bool f32 = XD ? (flags[1] != 0) : false;
  for (int idx = tid; idx < 64 * KD / 8; idx += 256) {
    int r = idx / (KD / 8), k8 = idx - r * (KD / 8);
    int m = m0 + r;
    uint4 v = make_uint4(0, 0, 0, 0);
    if (m < N) {
      if (XD && f32) {
        const float4 v0 = *((const float4*)inv + ((size_t)m * KD + k8 * 8) / 4);
        const float4 v1 = *((const float4*)inv + ((size_t)m * KD + k8 * 8) / 4 + 1);
        v = make_uint4(pk2(v0.x, v0.y), pk2(v0.z, v0.w),
                       pk2(v1.x, v1.y), pk2(v1.z, v1.w));
      } else {
        v = *((const uint4*)inv + ((size_t)m * KD + k8 * 8) / 8);
      }
    }
    *(uint4*)(sA + r * SA + k8 * 8) = v;
  }
  __syncthreads();
  const int lane = tid & 63;
  const int wv = tid >> 6;
  const int lr = lane & 15;
  const int q = lane >> 4;
  f32x4 acc[NT];
#pragma unroll
  for (int t = 0; t < NT; ++t)
#pragma unroll
    for (int r = 0; r < 4; ++r) acc[t][r] = 0.f;
  const int arow = wv * 16 + lr;
#pragma unroll
  for (int ks = 0; ks < KS; ++ks) {
    const int k0 = ks * 32 + q * 8;
    const bf16x8 a = *(const bf16x8*)(sA + arow * SA + k0);
#pragma unroll
    for (int t = 0; t < NT; ++t) {
      const bf16x8 b = BG ? *(const bf16x8*)(wt + (t * 16 + lr) * KD + k0)
                          : *(const bf16x8*)(sB + (t * 16 + lr) * SA + k0);
      acc[t] = __builtin_amdgcn_mfma_f32_16x16x32_bf16(a, b, acc[t], 0, 0, 0);
    }
  }
  // al epilogue: row-dots with a_s/a_d, reduce over 16 col-lanes
  float ps[4] = {0.f, 0.f, 0.f, 0.f}, pd[4] = {0.f, 0.f, 0.f, 0.f};
#pragma unroll
  for (int t = 0; t < NT; ++t) {
    const float av = a_s[t * 16 + lr];
    const float dv = a_d[t * 16 + lr];
#pragma unroll
    for (int r = 0; r < 4; ++r) {
      ps[r] = fmaf(acc[t][r], av, ps[r]);
      pd[r] = fmaf(acc[t][r], dv, pd[r]);
    }
  }
#pragma unroll
  for (int m = 1; m < 16; m <<= 1)
#pragma unroll
    for (int r = 0; r < 4; ++r) {
      ps[r] += __shfl_xor(ps[r], m, 64);
      pd[r] += __shfl_xor(pd[r], m, 64);
    }
  const int mb = m0 + wv * 16 + q * 4;
  if (lr == 0) {
#pragma unroll
    for (int r = 0; r < 4; ++r) {
      int m = mb + r;
      if (m < N) { als[m] = ps[r]; ald[m] = pd[r]; }
    }
  }
#pragma unroll
  for (int t = 0; t < NT; ++t)
#pragma unroll
    for (int r = 0; r < 4; ++r) {
      int m = mb + r;
      if (m < N) h[(size_t)m * DOUT + t * 16 + lr] = __float2bfloat16(acc[t][r]);
    }
}

// ---- aggregate body: out[d][j] = softmax-weighted gather + bias -----------
template <int DOUT, bool RELU, bool FINAL>
__device__ __forceinline__ void agg_body(int bb, const int* __restrict__ rowptr,
                                         const int* __restrict__ ssrt,
                                         const float* __restrict__ als,
                                         const float* __restrict__ ald,
                                         const unsigned short* __restrict__ hb,
                                         const float* __restrict__ bias,
                                         bf16* __restrict__ outb,
                                         void* __restrict__ outv,
                                         const int* __restrict__ flags) {
  constexpr int TPN = DOUT / 8;
  constexpr int NPB = 256 / TPN;
  const int sub = threadIdx.x % TPN;
  const int d = bb * NPB + threadIdx.x / TPN;
  if (d >= N) return;                 // no __syncthreads below: safe
  const int p0 = rowptr[d], p1 = rowptr[d + 1];
  const float ad = ald[d];
  const int col0 = sub * 8;
  float acc[8];
#pragma unroll
  for (int c = 0; c < 8; ++c) acc[c] = 0.f;
  float sum = 0.f;
  int p = p0;
  for (; p + 4 <= p1; p += 4) {
    const int s0 = ssrt[p + 0];
    const int s1 = ssrt[p + 1];
    const int s2 = ssrt[p + 2];
    const int s3 = ssrt[p + 3];
    const uint4 r0 = *reinterpret_cast<const uint4*>(hb + (size_t)s0 * DOUT + col0);
    const uint4 r1 = *reinterpret_cast<const uint4*>(hb + (size_t)s1 * DOUT + col0);
    const uint4 r2 = *reinterpret_cast<const uint4*>(hb + (size_t)s2 * DOUT + col0);
    const uint4 r3 = *reinterpret_cast<const uint4*>(hb + (size_t)s3 * DOUT + col0);
    const float x0 = edge_ex(als[s0] + ad);
    const float x1 = edge_ex(als[s1] + ad);
    const float x2 = edge_ex(als[s2] + ad);
    const float x3 = edge_ex(als[s3] + ad);
    sum += (x0 + x1) + (x2 + x3);
    fma8(r0, x0, acc);
    fma8(r1, x1, acc);
    fma8(r2, x2, acc);
    fma8(r3, x3, acc);
  }
  for (; p < p1; ++p) {
    const int s = ssrt[p];
    const uint4 r = *reinterpret_cast<const uint4*>(hb + (size_t)s * DOUT + col0);
    const float x = edge_ex(als[s] + ad);
    sum += x;
    fma8(r, x, acc);
  }
  const float inv = 1.f / sum;
  if (FINAL) {
    const bool f32o = flags[1] != 0;
#pragma unroll
    for (int c = 0; c < 8; ++c) {
      float v = acc[c] * inv + bias[col0 + c];
      if (f32o) ((float*)outv)[(size_t)d * DOUT + col0 + c] = v;
      else      ((bf16*)outv)[(size_t)d * DOUT + col0 + c] = __float2bfloat16(v);
    }
  } else {
#pragma unroll
    for (int c = 0; c < 8; ++c) {
      float v = acc[c] * inv + bias[col0 + c];
      if (RELU) v = (v > 0.f) ? v : 0.f;
      outb[(size_t)d * DOUT + col0 + c] = __float2bfloat16(v);
    }
  }
}

// ---- the persistent cooperative pipeline ----------------------------------
static constexpr int GB1 = (N + 63) / 64;     // 1563 gemm tiles
static constexpr int AG1 = (N + 15) / 16;     // 6250
static constexpr int AG2 = (N + 31) / 32;     // 3125
static constexpr int AG3 = (N + 127) / 128;   // 782

struct MArgs {
  const int* ei32; const long long* ei64; const int* flags;
  const int* off1; int2* tmp; int* rowptr; int* ssrt;
  const void* x;
  const unsigned short* w1t; const unsigned short* w2t; const unsigned short* w3t;
  const float *as1, *ad1, *b1, *as2, *ad2, *b2, *as3, *ad3, *b3;
  bf16* hbuf; bf16* obuf; float* als; float* ald; void* dout;
};

__global__ __launch_bounds__(256, 4) void mega_kernel(MArgs a) {
  cg::grid_group grid = cg::this_grid();
  __shared__ __align__(16) char smem[34816];        // sA(17408) + sB(17408)
  unsigned short* sA = (unsigned short*)smem;
  unsigned short* sB = (unsigned short*)(smem + 17408);
  const int nb = gridDim.x;

  // S0: layer-1 GEMM(+al, direct-from-x, B-from-global) || coarse scatter
  for (int u = blockIdx.x; u < GB1 + NCHK; u += nb) {
    if (u < GB1)
      gemm_body<128, 128, true, true>(u, a.x, a.flags, a.w1t, a.hbuf,
                                      a.as1, a.ad1, a.als, a.ald, sA, sB);
    else
      phaseC_body(u - GB1, a.ei32, a.ei64, a.flags[0], a.off1, a.tmp, (int*)smem);
    __syncthreads();
  }
  grid.sync();
  // S1: per-bucket fine sort -> rowptr + ssrt
  for (int u = blockIdx.x; u < NB1; u += nb) {
    phaseD_body(u, a.off1, a.tmp, a.rowptr, a.ssrt, (int*)smem);
    __syncthreads();
  }
  grid.sync();
  // S2: aggregate L1
  for (int u = blockIdx.x; u < AG1; u += nb)
    agg_body<128, true, false>(u, a.rowptr, a.ssrt, a.als, a.ald,
                               (const unsigned short*)a.hbuf, a.b1, a.obuf,
                               nullptr, a.flags);
  grid.sync();
  // S3: layer-2 GEMM(+al)
  for (int u = blockIdx.x; u < GB1; u += nb) {
    gemm_body<128, 64, false, false>(u, a.obuf, a.flags, a.w2t, a.hbuf,
                                     a.as2, a.ad2, a.als, a.ald, sA, sB);
    __syncthreads();
  }
  grid.sync();
  // S4: aggregate L2
  for (int u = blockIdx.x; u < AG2; u += nb)
    agg_body<64, true, false>(u, a.rowptr, a.ssrt, a.als, a.ald,
                              (const unsigned short*)a.hbuf, a.b2, a.obuf,
                              nullptr, a.flags);
  grid.sync();
  // S5: layer-3 GEMM(+al)
  for (int u = blockIdx.x; u < GB1; u += nb) {
    gemm_body<64, 16, false, false>(u, a.obuf, a.flags, a.w3t, a.hbuf,
                                    a.as3, a.ad3, a.als, a.ald, sA, sB);
    __syncthreads();
  }
  grid.sync();
  // S6: aggregate L3 -> d_out (dtype per flags[1])
  for (int u = blockIdx.x; u < AG3; u += nb)
    agg_body<16, false, true>(u, a.rowptr, a.ssrt, a.als, a.ald,
                              (const unsigned short*)a.hbuf, a.b3, nullptr,
                              a.dout, a.flags);
}

static inline size_t rup(size_t v) { return (v + 255) & ~(size_t)255; }

extern "C" void kernel_launch(void* const* d_in, const int* in_sizes, int n_in,
                              void* d_out, int out_size, void* d_ws, size_t ws_size,
                              hipStream_t stream) {
  const int* ei32 = (const int*)d_in[1];
  const long long* ei64 = (const long long*)d_in[1];

  char* p = (char*)d_ws;
  int*   flags  = (int*)p;   p += 256;
  float* prm    = (float*)p; p += rup((size_t)PTOT * 4);
  bf16*  w1t    = (bf16*)p;  p += rup((size_t)128 * 128 * 2);
  bf16*  w2t    = (bf16*)p;  p += rup((size_t)128 * 64 * 2);
  bf16*  w3t    = (bf16*)p;  p += rup((size_t)64 * 16 * 2);
  float* als    = (float*)p; p += rup((size_t)N * 4);
  float* ald    = (float*)p; p += rup((size_t)N * 4);
  int*   rowptr = (int*)p;   p += rup((size_t)(N + 1) * 4);
  int*   c1     = (int*)p;   p += rup((size_t)M1 * 4);
  int*   off1   = (int*)p;   p += rup((size_t)M1 * 4);
  int*   bsum   = (int*)p;   p += rup((size_t)SBLK * 4);
  int*   boff   = (int*)p;   p += rup((size_t)SBLK * 4);
  int2*  tmp    = (int2*)p;  p += rup((size_t)ETOT * 8);
  int*   ssrt   = (int*)p;   p += rup((size_t)ETOT * 4);
  bf16*  obuf   = (bf16*)p;  p += rup((size_t)N * 128 * 2);
  bf16*  hbuf   = (bf16*)p;  // + 25.6 MB -> total ~73 MB (ws proven >= 99 MB)

  Src12 s;
  for (int i = 0; i < 12; ++i) s.p[i] = d_in[2 + i];

  // 1) flags (parallel ballots, 1 block)
  detect_kernel<<<1, 256, 0, stream>>>(
      (const unsigned long long*)d_in[1], (const unsigned short*)d_in[2], flags);
  // 2) coarse LDS histograms || param/W converts
  prep_kernel<<<PB_TOT, 256, 0, stream>>>(ei32, ei64, flags, c1, s, prm, w1t, w2t, w3t);
  // 3-5) scan of c1 -> off1
  scanA_kernel<<<SBLK, 256, 0, stream>>>(c1, bsum);
  scanB_kernel<<<1, 256, 0, stream>>>(bsum, boff);
  scanC_kernel<<<SBLK, 256, 0, stream>>>(c1, boff, off1);

  // 6) the whole layer pipeline: one persistent cooperative kernel
  MArgs ma;
  ma.ei32 = ei32; ma.ei64 = ei64; ma.flags = flags;
  ma.off1 = off1; ma.tmp = tmp; ma.rowptr = rowptr; ma.ssrt = ssrt;
  ma.x = d_in[0];
  ma.w1t = (const unsigned short*)w1t;
  ma.w2t = (const unsigned short*)w2t;
  ma.w3t = (const unsigned short*)w3t;
  ma.as1 = prm + H_POFF[1];  ma.ad1 = prm + H_POFF[2];  ma.b1 = prm + H_POFF[3];
  ma.as2 = prm + H_POFF[5];  ma.ad2 = prm + H_POFF[6];  ma.b2 = prm + H_POFF[7];
  ma.as3 = prm + H_POFF[9];  ma.ad3 = prm + H_POFF[10]; ma.b3 = prm + H_POFF[11];
  ma.hbuf = hbuf; ma.obuf = obuf; ma.als = als; ma.ald = ald; ma.dout = d_out;

  int nblk = 0;
  hipError_t e1 = hipOccupancyMaxActiveBlocksPerMultiprocessor(
      &nblk, (const void*)mega_kernel, 256, 0);
  if (e1 != hipSuccess || nblk < 1) nblk = 2;  // LDS 34.8 KB always allows >= 2
  int ncu = 256;
  int dev = 0;
  if (hipGetDevice(&dev) == hipSuccess) {
    hipError_t e2 = hipDeviceGetAttribute(&ncu, hipDeviceAttributeMultiprocessorCount, dev);
    if (e2 != hipSuccess || ncu < 1) ncu = 256;
  }
  int grid = nblk * ncu;
  void* kargs[] = {&ma};
  hipError_t e3 = hipLaunchCooperativeKernel((void*)mega_kernel, dim3(grid),
                                             dim3(256), kargs, 0, stream);
  (void)e3;
}

// Round 13
// 343.854 us; speedup vs baseline: 2.3723x; 2.3723x over previous
//
#include <hip/hip_runtime.h>
#include <hip/hip_bf16.h>

typedef __hip_bfloat16 bf16;
typedef __attribute__((ext_vector_type(8))) __bf16 bf16x8;
typedef __attribute__((ext_vector_type(4))) float f32x4;

static constexpr int N = 100000;
static constexpr int E = 1600000;
static constexpr int ETOT = E + N;   // self-loops appended after the E edges
static constexpr float SLOPE = 0.2f;

// ---- param table: W1,as1,ad1,b1, W2,as2,ad2,b2, W3,as3,ad3,b3 (fp32 flat) --
__device__ __constant__ int c_poff[12] = {0, 16384, 16512, 16640,
                                          16768, 24960, 25024, 25088,
                                          25152, 26176, 26192, 26208};
static constexpr int PTOT = 26224;
static constexpr int H_POFF[12] = {0, 16384, 16512, 16640, 16768, 24960,
                                   25024, 25088, 25152, 26176, 26192, 26208};

struct Src12 { const void* p[12]; };

__device__ __forceinline__ float bfLo(unsigned u) { return __uint_as_float(u << 16); }
__device__ __forceinline__ float bfHi(unsigned u) { return __uint_as_float(u & 0xFFFF0000u); }

__device__ __forceinline__ void fma8(const uint4 r, float e, float* acc) {
  acc[0] = fmaf(e, bfLo(r.x), acc[0]);
  acc[1] = fmaf(e, bfHi(r.x), acc[1]);
  acc[2] = fmaf(e, bfLo(r.y), acc[2]);
  acc[3] = fmaf(e, bfHi(r.y), acc[3]);
  acc[4] = fmaf(e, bfLo(r.z), acc[4]);
  acc[5] = fmaf(e, bfHi(r.z), acc[5]);
  acc[6] = fmaf(e, bfLo(r.w), acc[6]);
  acc[7] = fmaf(e, bfHi(r.w), acc[7]);
}

__device__ __forceinline__ float edge_ex(float l) {
  l = (l > 0.f) ? l : SLOPE * l;
  return __expf(l);
}

__device__ __forceinline__ void loadEdge(const int* __restrict__ ei32,
                                         const long long* __restrict__ ei64,
                                         int use64, int t, int& s, int& d) {
  if (t >= E) { s = d = t - E; return; }
  if (use64) { s = (int)ei64[t]; d = (int)ei64[E + t]; }
  else       { s = ei32[t];      d = ei32[E + t]; }
}

__device__ __forceinline__ unsigned pk2(float a, float b) {
  bf16 x = __float2bfloat16(a), y = __float2bfloat16(b);
  unsigned short ux = *(unsigned short*)&x, uy = *(unsigned short*)&y;
  return ((unsigned)uy << 16) | ux;
}

// ---- bucket-sort geometry ----
static constexpr int CHUNK = 8192;
static constexpr int NCHK  = (ETOT + CHUNK - 1) / CHUNK;   // 208
static constexpr int NB1   = (N + 511) / 512;              // 196 coarse buckets
static constexpr int M1    = NB1 * NCHK;                   // 40768
static constexpr int SBLK  = (M1 + 255) / 256;             // 160

// ---- flags: flags[0]=edge idx is int64; flags[1]=float tensors are fp32 ---
__global__ __launch_bounds__(256) void detect_kernel(
    const unsigned long long* __restrict__ ei64,
    const unsigned short* __restrict__ w1u16, int* __restrict__ flags) {
  const int t = threadIdx.x;
  __shared__ unsigned long long bl[4];
  __shared__ unsigned long long sb64;
  const int w = t >> 6;
  bool p64 = (t < 64) && (ei64[t] >= (unsigned long long)N);
  unsigned long long b64 = __ballot(p64);
  if (t == 0) sb64 = b64;
  // W1 glorot-bounded (|v|<=0.154) -> bf16 exp field < 126; fp32 low halves
  // are random -> exp>=126 appears within 256 samples w.h.p.
  bool pf = (((w1u16[t] >> 7) & 0xFFu) >= 126u);
  unsigned long long bf_ = __ballot(pf);
  if ((t & 63) == 0) bl[w] = bf_;
  __syncthreads();
  if (t == 0) {
    flags[0] = (sb64 == 0ull) ? 1 : 0;
    flags[1] = ((bl[0] | bl[1] | bl[2] | bl[3]) != 0ull) ? 1 : 0;
  }
}

// ---- K2: phase A (coarse LDS histogram) || param/W converts ---------------
static constexpr int PB_PAR = (PTOT + 255) / 256;  // 103
static constexpr int PB_W1  = 128 * 128 / 256;     // 64
static constexpr int PB_W2  = 128 * 64 / 256;      // 32
static constexpr int PB_W3  = 64 * 16 / 256;       // 4
static constexpr int PB_TOT = NCHK + PB_PAR + PB_W1 + PB_W2 + PB_W3;

__device__ __forceinline__ void conv_w(const void* W, int kd, int dout, int f32,
                                       bf16* __restrict__ wt, int idx) {
  int n = idx / kd, k = idx - n * kd;
  float v = f32 ? ((const float*)W)[k * dout + n]
                : __bfloat162float(((const bf16*)W)[k * dout + n]);
  wt[idx] = __float2bfloat16(v);
}

__global__ __launch_bounds__(256) void prep_kernel(
    const int* __restrict__ ei32, const long long* __restrict__ ei64,
    const int* __restrict__ flags, int* __restrict__ c1,
    Src12 s, float* __restrict__ prm,
    bf16* __restrict__ w1t, bf16* __restrict__ w2t, bf16* __restrict__ w3t) {
  const int b = blockIdx.x, tid = threadIdx.x;
  const int f64 = flags[0], f32 = flags[1];
  if (b < NCHK) {
    __shared__ int h1[NB1];
    if (tid < NB1) h1[tid] = 0;
    __syncthreads();
    const int t0 = b * CHUNK;
#pragma unroll 4
    for (int i = tid; i < CHUNK; i += 256) {
      int t = t0 + i;
      if (t < ETOT) {
        int d = (t >= E) ? (t - E) : (f64 ? (int)ei64[E + t] : ei32[E + t]);
        atomicAdd(&h1[d >> 9], 1);
      }
    }
    __syncthreads();
    if (tid < NB1) c1[tid * NCHK + b] = h1[tid];   // bin-major
  } else if (b < NCHK + PB_PAR) {
    int t = (b - NCHK) * 256 + tid;
    if (t < PTOT) {
      int k = 0;
#pragma unroll
      for (int i = 1; i < 12; ++i)
        if (t >= c_poff[i]) k = i;
      int j = t - c_poff[k];
      prm[t] = f32 ? ((const float*)s.p[k])[j]
                   : __bfloat162float(((const bf16*)s.p[k])[j]);
    }
  } else if (b < NCHK + PB_PAR + PB_W1) {
    conv_w(s.p[0], 128, 128, f32, w1t, (b - NCHK - PB_PAR) * 256 + tid);
  } else if (b < NCHK + PB_PAR + PB_W1 + PB_W2) {
    conv_w(s.p[4], 128, 64, f32, w2t, (b - NCHK - PB_PAR - PB_W1) * 256 + tid);
  } else {
    conv_w(s.p[8], 64, 16, f32, w3t, (b - NCHK - PB_PAR - PB_W1 - PB_W2) * 256 + tid);
  }
}

// ---- 3-phase exclusive scan of c1[0..M1) -> off1 --------------------------
__global__ __launch_bounds__(256) void scanA_kernel(const int* __restrict__ c1,
                                                    int* __restrict__ bsum) {
  __shared__ int red[256];
  const int t = threadIdx.x;
  const int i = blockIdx.x * 256 + t;
  red[t] = (i < M1) ? c1[i] : 0;
  __syncthreads();
#pragma unroll
  for (int off = 128; off > 0; off >>= 1) {
    if (t < off) red[t] += red[t + off];
    __syncthreads();
  }
  if (t == 0) bsum[blockIdx.x] = red[0];
}

__global__ __launch_bounds__(256) void scanB_kernel(const int* __restrict__ bsum,
                                                    int* __restrict__ boff) {
  __shared__ int s[256];
  const int t = threadIdx.x;
  const int v = (t < SBLK) ? bsum[t] : 0;
  s[t] = v;
  __syncthreads();
  for (int off = 1; off < 256; off <<= 1) {
    int u = (t >= off) ? s[t - off] : 0;
    __syncthreads();
    s[t] += u;
    __syncthreads();
  }
  if (t < SBLK) boff[t] = s[t] - v;
}

__global__ __launch_bounds__(256) void scanC_kernel(const int* __restrict__ c1,
                                                    const int* __restrict__ boff,
                                                    int* __restrict__ off1) {
  __shared__ int s[256];
  const int t = threadIdx.x;
  const int i = blockIdx.x * 256 + t;
  const int v = (i < M1) ? c1[i] : 0;
  s[t] = v;
  __syncthreads();
#pragma unroll
  for (int off = 1; off < 256; off <<= 1) {
    int u = (t >= off) ? s[t - off] : 0;
    __syncthreads();
    s[t] += u;
    __syncthreads();
  }
  if (i < M1) off1[i] = boff[blockIdx.x] + s[t] - v;
}

// ---- phase C body: scatter edges into coarse buckets via LDS cursors ------
__device__ __forceinline__ void phaseC_body(int c, const int* __restrict__ ei32,
                                            const long long* __restrict__ ei64,
                                            int f64, const int* __restrict__ off1,
                                            int2* __restrict__ tmp) {
  __shared__ int cur[NB1];
  const int tid = threadIdx.x;
  if (tid < NB1) cur[tid] = off1[tid * NCHK + c];
  __syncthreads();
  const int t0 = c * CHUNK;
#pragma unroll 4
  for (int i = tid; i < CHUNK; i += 256) {
    int t = t0 + i;
    if (t < ETOT) {
      int s, d;
      loadEdge(ei32, ei64, f64, t, s, d);
      int pos = atomicAdd(&cur[d >> 9], 1);
      tmp[pos] = make_int2(d, s);
    }
  }
}

// ---- phase D: per-bucket fine counting sort -> rowptr + ssrt --------------
__global__ __launch_bounds__(256) void phaseD_kernel(const int* __restrict__ off1,
                                                     const int2* __restrict__ tmp,
                                                     int* __restrict__ rowptr,
                                                     int* __restrict__ ssrt) {
  __shared__ int h2[512], e2[512], cur[512];
  __shared__ int ps[256];
  const int b = blockIdx.x, t = threadIdx.x;
  const int base = off1[b * NCHK];
  const int end = (b + 1 < NB1) ? off1[(b + 1) * NCHK] : ETOT;
  const int len = end - base;
  h2[2 * t] = 0; h2[2 * t + 1] = 0;
  __syncthreads();
  for (int i = t; i < len; i += 256)
    atomicAdd(&h2[tmp[base + i].x & 511], 1);
  __syncthreads();
  const int s1 = h2[2 * t], s2 = h2[2 * t + 1];
  ps[t] = s1 + s2;
  __syncthreads();
  for (int off = 1; off < 256; off <<= 1) {
    int u = (t >= off) ? ps[t - off] : 0;
    __syncthreads();
    ps[t] += u;
    __syncthreads();
  }
  const int ep = ps[t] - (s1 + s2);
  e2[2 * t] = ep;
  e2[2 * t + 1] = ep + s1;
  cur[2 * t] = ep;
  cur[2 * t + 1] = ep + s1;
  __syncthreads();
#pragma unroll
  for (int k = 0; k < 2; ++k) {
    int f = 2 * t + k;
    int node = (b << 9) + f;
    if (node < N) rowptr[node] = base + e2[f];
  }
  if (b == 0 && t == 0) rowptr[N] = ETOT;
  for (int i = t; i < len; i += 256) {
    int2 e = tmp[base + i];
    int pos = base + atomicAdd(&cur[e.x & 511], 1);
    ssrt[pos] = e.y;
  }
}

// -------- MFMA GEMM body (64 rows x DOUT) + fused al epilogue --------------
// XD: stage A directly from x (fp32/bf16 per flags[1]). B staged in LDS.
template <int KD, int DOUT, bool XD>
__device__ __forceinline__ void gemm_body(int bb, const void* __restrict__ inv,
                                          const int* __restrict__ flags,
                                          const unsigned short* __restrict__ wt,
                                          bf16* __restrict__ h,
                                          const float* __restrict__ a_s,
                                          const float* __restrict__ a_d,
                                          float* __restrict__ als,
                                          float* __restrict__ ald) {
  constexpr int SA = KD + 8;
  constexpr int NT = DOUT / 16;
  constexpr int KS = KD / 32;
  __shared__ unsigned short sA[64 * SA];
  __shared__ unsigned short sB[DOUT * SA];
  const int tid = threadIdx.x;
  const int m0 = bb * 64;
  for (int idx = tid; idx < DOUT * KD / 8; idx += 256) {
    int n = idx / (KD / 8), k8 = idx - n * (KD / 8);
    *(uint4*)(sB + n * SA + k8 * 8) = *(const uint4*)(wt + n * KD + k8 * 8);
  }
  const bool f32 = XD ? (flags[1] != 0) : false;
  for (int idx = tid; idx < 64 * KD / 8; idx += 256) {
    int r = idx / (KD / 8), k8 = idx - r * (KD / 8);
    int m = m0 + r;
    uint4 v = make_uint4(0, 0, 0, 0);
    if (m < N) {
      if (XD && f32) {
        const float4 v0 = *((const float4*)inv + ((size_t)m * KD + k8 * 8) / 4);
        const float4 v1 = *((const float4*)inv + ((size_t)m * KD + k8 * 8) / 4 + 1);
        v = make_uint4(pk2(v0.x, v0.y), pk2(v0.z, v0.w),
                       pk2(v1.x, v1.y), pk2(v1.z, v1.w));
      } else {
        v = *((const uint4*)inv + ((size_t)m * KD + k8 * 8) / 8);
      }
    }
    *(uint4*)(sA + r * SA + k8 * 8) = v;
  }
  __syncthreads();
  const int lane = tid & 63;
  const int wv = tid >> 6;
  const int lr = lane & 15;
  const int q = lane >> 4;
  f32x4 acc[NT];
#pragma unroll
  for (int t = 0; t < NT; ++t)
#pragma unroll
    for (int r = 0; r < 4; ++r) acc[t][r] = 0.f;
  const int arow = wv * 16 + lr;
#pragma unroll
  for (int ks = 0; ks < KS; ++ks) {
    const int k0 = ks * 32 + q * 8;
    const bf16x8 a = *(const bf16x8*)(sA + arow * SA + k0);
#pragma unroll
    for (int t = 0; t < NT; ++t) {
      const bf16x8 b = *(const bf16x8*)(sB + (t * 16 + lr) * SA + k0);
      acc[t] = __builtin_amdgcn_mfma_f32_16x16x32_bf16(a, b, acc[t], 0, 0, 0);
    }
  }
  float ps[4] = {0.f, 0.f, 0.f, 0.f}, pd[4] = {0.f, 0.f, 0.f, 0.f};
#pragma unroll
  for (int t = 0; t < NT; ++t) {
    const float av = a_s[t * 16 + lr];
    const float dv = a_d[t * 16 + lr];
#pragma unroll
    for (int r = 0; r < 4; ++r) {
      ps[r] = fmaf(acc[t][r], av, ps[r]);
      pd[r] = fmaf(acc[t][r], dv, pd[r]);
    }
  }
#pragma unroll
  for (int m = 1; m < 16; m <<= 1)
#pragma unroll
    for (int r = 0; r < 4; ++r) {
      ps[r] += __shfl_xor(ps[r], m, 64);
      pd[r] += __shfl_xor(pd[r], m, 64);
    }
  const int mb = m0 + wv * 16 + q * 4;
  if (lr == 0) {
#pragma unroll
    for (int r = 0; r < 4; ++r) {
      int m = mb + r;
      if (m < N) { als[m] = ps[r]; ald[m] = pd[r]; }
    }
  }
#pragma unroll
  for (int t = 0; t < NT; ++t)
#pragma unroll
    for (int r = 0; r < 4; ++r) {
      int m = mb + r;
      if (m < N) h[(size_t)m * DOUT + t * 16 + lr] = __float2bfloat16(acc[t][r]);
    }
}

// layer-1 GEMM (direct from x) fused with bucket phase C (independent tasks)
static constexpr int GB1 = (N + 63) / 64;  // 1563

__global__ __launch_bounds__(256) void gemm1_phaseC(
    const void* __restrict__ x, const int* __restrict__ flags,
    const unsigned short* __restrict__ wt, bf16* __restrict__ h,
    const float* __restrict__ a_s, const float* __restrict__ a_d,
    float* __restrict__ als, float* __restrict__ ald,
    const int* __restrict__ ei32, const long long* __restrict__ ei64,
    const int* __restrict__ off1, int2* __restrict__ tmp) {
  if (blockIdx.x < GB1) {
    gemm_body<128, 128, true>(blockIdx.x, x, flags, wt, h, a_s, a_d, als, ald);
  } else {
    int c = blockIdx.x - GB1;
    if (c < NCHK) phaseC_body(c, ei32, ei64, flags[0], off1, tmp);
  }
}

// ---- fused aggregate (DA cols in) -> GEMM (DA x DOUT) per 128-node tile ----
// agg results land directly in the GEMM's LDS A-tile; no global round-trip.
// Block-local fusion: the agg of a tile produces exactly that tile's A rows.
static constexpr int AB = (N + 127) / 128;   // 782 tiles

template <int DA, int DOUT>
__global__ __launch_bounds__(512) void aggemm_kernel(
    const int* __restrict__ rowptr, const int* __restrict__ ssrt,
    const float* __restrict__ als_in, const float* __restrict__ ald_in,
    const unsigned short* __restrict__ hin, const float* __restrict__ bias,
    const unsigned short* __restrict__ wt, bf16* __restrict__ hout,
    const float* __restrict__ a_s, const float* __restrict__ a_d,
    float* __restrict__ als_out, float* __restrict__ ald_out) {
  constexpr int SA = DA + 8;
  constexpr int TPN = DA / 8;         // 16 / 8
  constexpr int NPR = 512 / TPN;      // 32 / 64 nodes per round
  constexpr int NR = 128 / NPR;       // 4 / 2 rounds
  constexpr int NT = DOUT / 16;       // 4 / 1
  constexpr int KS = DA / 32;         // 4 / 2
  __shared__ unsigned short sA[128 * SA];
  __shared__ unsigned short sB[DOUT * SA];
  const int tid = threadIdx.x;
  const int m0 = blockIdx.x * 128;
  for (int idx = tid; idx < DOUT * DA / 8; idx += 512) {
    int n = idx / (DA / 8), k8 = idx - n * (DA / 8);
    *(uint4*)(sB + n * SA + k8 * 8) = *(const uint4*)(wt + n * DA + k8 * 8);
  }
  // agg phase: softmax-weighted gather + bias + ReLU -> bf16 packed into sA
  const int sub = tid % TPN;
  const int rr0 = tid / TPN;
  const int col0 = sub * 8;
#pragma unroll
  for (int r = 0; r < NR; ++r) {
    const int row = r * NPR + rr0;
    const int d = m0 + row;
    if (d < N) {
      const int p0 = rowptr[d], p1 = rowptr[d + 1];
      const float ad = ald_in[d];
      float acc[8];
#pragma unroll
      for (int c = 0; c < 8; ++c) acc[c] = 0.f;
      float sum = 0.f;
      int p = p0;
      for (; p + 4 <= p1; p += 4) {
        const int s0 = ssrt[p + 0];
        const int s1 = ssrt[p + 1];
        const int s2 = ssrt[p + 2];
        const int s3 = ssrt[p + 3];
        const uint4 r0 = *reinterpret_cast<const uint4*>(hin + (size_t)s0 * DA + col0);
        const uint4 r1 = *reinterpret_cast<const uint4*>(hin + (size_t)s1 * DA + col0);
        const uint4 r2 = *reinterpret_cast<const uint4*>(hin + (size_t)s2 * DA + col0);
        const uint4 r3 = *reinterpret_cast<const uint4*>(hin + (size_t)s3 * DA + col0);
        const float x0 = edge_ex(als_in[s0] + ad);
        const float x1 = edge_ex(als_in[s1] + ad);
        const float x2 = edge_ex(als_in[s2] + ad);
        const float x3 = edge_ex(als_in[s3] + ad);
        sum += (x0 + x1) + (x2 + x3);
        fma8(r0, x0, acc);
        fma8(r1, x1, acc);
        fma8(r2, x2, acc);
        fma8(r3, x3, acc);
      }
      for (; p < p1; ++p) {
        const int s = ssrt[p];
        const uint4 rr = *reinterpret_cast<const uint4*>(hin + (size_t)s * DA + col0);
        const float x = edge_ex(als_in[s] + ad);
        sum += x;
        fma8(rr, x, acc);
      }
      const float inv = 1.f / sum;
      float v[8];
#pragma unroll
      for (int c = 0; c < 8; ++c) {
        float w = acc[c] * inv + bias[col0 + c];
        v[c] = (w > 0.f) ? w : 0.f;   // ReLU between layers
      }
      uint4 pk = make_uint4(pk2(v[0], v[1]), pk2(v[2], v[3]),
                            pk2(v[4], v[5]), pk2(v[6], v[7]));
      *(uint4*)(sA + row * SA + col0) = pk;
    }
  }
  __syncthreads();
  // gemm phase: 8 waves x 16 rows = 128 rows
  const int lane = tid & 63;
  const int wv = tid >> 6;
  const int lr = lane & 15;
  const int q = lane >> 4;
  f32x4 acc[NT];
#pragma unroll
  for (int t = 0; t < NT; ++t)
#pragma unroll
    for (int r = 0; r < 4; ++r) acc[t][r] = 0.f;
  const int arow = wv * 16 + lr;
#pragma unroll
  for (int ks = 0; ks < KS; ++ks) {
    const int k0 = ks * 32 + q * 8;
    const bf16x8 a = *(const bf16x8*)(sA + arow * SA + k0);
#pragma unroll
    for (int t = 0; t < NT; ++t) {
      const bf16x8 b = *(const bf16x8*)(sB + (t * 16 + lr) * SA + k0);
      acc[t] = __builtin_amdgcn_mfma_f32_16x16x32_bf16(a, b, acc[t], 0, 0, 0);
    }
  }
  float ps[4] = {0.f, 0.f, 0.f, 0.f}, pd[4] = {0.f, 0.f, 0.f, 0.f};
#pragma unroll
  for (int t = 0; t < NT; ++t) {
    const float av = a_s[t * 16 + lr];
    const float dv = a_d[t * 16 + lr];
#pragma unroll
    for (int r = 0; r < 4; ++r) {
      ps[r] = fmaf(acc[t][r], av, ps[r]);
      pd[r] = fmaf(acc[t][r], dv, pd[r]);
    }
  }
#pragma unroll
  for (int m = 1; m < 16; m <<= 1)
#pragma unroll
    for (int r = 0; r < 4; ++r) {
      ps[r] += __shfl_xor(ps[r], m, 64);
      pd[r] += __shfl_xor(pd[r], m, 64);
    }
  const int mb = m0 + wv * 16 + q * 4;
  if (lr == 0) {
#pragma unroll
    for (int r = 0; r < 4; ++r) {
      int m = mb + r;
      if (m < N) { als_out[m] = ps[r]; ald_out[m] = pd[r]; }
    }
  }
#pragma unroll
  for (int t = 0; t < NT; ++t)
#pragma unroll
    for (int r = 0; r < 4; ++r) {
      int m = mb + r;
      if (m < N) hout[(size_t)m * DOUT + t * 16 + lr] = __float2bfloat16(acc[t][r]);
    }
}

// ---- final aggregate (layer 3) -> d_out -----------------------------------
template <int DOUT>
__global__ __launch_bounds__(256) void agg_final(const int* __restrict__ rowptr,
                                                 const int* __restrict__ ssrt,
                                                 const float* __restrict__ als,
                                                 const float* __restrict__ ald,
                                                 const unsigned short* __restrict__ hb,
                                                 const float* __restrict__ bias,
                                                 void* __restrict__ outv,
                                                 const int* __restrict__ flags) {
  constexpr int TPN = DOUT / 8;          // 2
  constexpr int NPB = 256 / TPN;         // 128
  const int sub = threadIdx.x % TPN;
  const int d = blockIdx.x * NPB + threadIdx.x / TPN;
  if (d >= N) return;
  const int p0 = rowptr[d], p1 = rowptr[d + 1];
  const float ad = ald[d];
  const int col0 = sub * 8;
  float acc[8];
#pragma unroll
  for (int c = 0; c < 8; ++c) acc[c] = 0.f;
  float sum = 0.f;
  int p = p0;
  for (; p + 4 <= p1; p += 4) {
    const int s0 = ssrt[p + 0];
    const int s1 = ssrt[p + 1];
    const int s2 = ssrt[p + 2];
    const int s3 = ssrt[p + 3];
    const uint4 r0 = *reinterpret_cast<const uint4*>(hb + (size_t)s0 * DOUT + col0);
    const uint4 r1 = *reinterpret_cast<const uint4*>(hb + (size_t)s1 * DOUT + col0);
    const uint4 r2 = *reinterpret_cast<const uint4*>(hb + (size_t)s2 * DOUT + col0);
    const uint4 r3 = *reinterpret_cast<const uint4*>(hb + (size_t)s3 * DOUT + col0);
    const float x0 = edge_ex(als[s0] + ad);
    const float x1 = edge_ex(als[s1] + ad);
    const float x2 = edge_ex(als[s2] + ad);
    const float x3 = edge_ex(als[s3] + ad);
    sum += (x0 + x1) + (x2 + x3);
    fma8(r0, x0, acc);
    fma8(r1, x1, acc);
    fma8(r2, x2, acc);
    fma8(r3, x3, acc);
  }
  for (; p < p1; ++p) {
    const int s = ssrt[p];
    const uint4 r = *reinterpret_cast<const uint4*>(hb + (size_t)s * DOUT + col0);
    const float x = edge_ex(als[s] + ad);
    sum += x;
    fma8(r, x, acc);
  }
  const float inv = 1.f / sum;
  const bool f32o = flags[1] != 0;
#pragma unroll
  for (int c = 0; c < 8; ++c) {
    float v = acc[c] * inv + bias[col0 + c];
    if (f32o) ((float*)outv)[(size_t)d * DOUT + col0 + c] = v;
    else      ((bf16*)outv)[(size_t)d * DOUT + col0 + c] = __float2bfloat16(v);
  }
}

static inline size_t rup(size_t v) { return (v + 255) & ~(size_t)255; }

extern "C" void kernel_launch(void* const* d_in, const int* in_sizes, int n_in,
                              void* d_out, int out_size, void* d_ws, size_t ws_size,
                              hipStream_t stream) {
  const int* ei32 = (const int*)d_in[1];
  const long long* ei64 = (const long long*)d_in[1];

  char* p = (char*)d_ws;
  int*   flags  = (int*)p;   p += 256;
  float* prm    = (float*)p; p += rup((size_t)PTOT * 4);
  bf16*  w1t    = (bf16*)p;  p += rup((size_t)128 * 128 * 2);
  bf16*  w2t    = (bf16*)p;  p += rup((size_t)128 * 64 * 2);
  bf16*  w3t    = (bf16*)p;  p += rup((size_t)64 * 16 * 2);
  float* als1   = (float*)p; p += rup((size_t)N * 4);
  float* ald1   = (float*)p; p += rup((size_t)N * 4);
  float* als2   = (float*)p; p += rup((size_t)N * 4);
  float* ald2   = (float*)p; p += rup((size_t)N * 4);
  float* als3   = (float*)p; p += rup((size_t)N * 4);
  float* ald3   = (float*)p; p += rup((size_t)N * 4);
  int*   rowptr = (int*)p;   p += rup((size_t)(N + 1) * 4);
  int*   c1     = (int*)p;   p += rup((size_t)M1 * 4);
  int*   off1   = (int*)p;   p += rup((size_t)M1 * 4);
  int*   bsum   = (int*)p;   p += rup((size_t)SBLK * 4);
  int*   boff   = (int*)p;   p += rup((size_t)SBLK * 4);
  int2*  tmp    = (int2*)p;  p += rup((size_t)ETOT * 8);
  int*   ssrt   = (int*)p;   p += rup((size_t)ETOT * 4);
  bf16*  h1     = (bf16*)p;  p += rup((size_t)N * 128 * 2);
  bf16*  h2     = (bf16*)p;  p += rup((size_t)N * 64 * 2);
  bf16*  h3     = (bf16*)p;  // + 3.2 MB -> total ~66 MB (ws proven >= 99 MB)

  Src12 s;
  for (int i = 0; i < 12; ++i) s.p[i] = d_in[2 + i];

  // 1) flags (parallel ballots, 1 block)
  detect_kernel<<<1, 256, 0, stream>>>(
      (const unsigned long long*)d_in[1], (const unsigned short*)d_in[2], flags);
  // 2) coarse LDS histograms || param/W converts
  prep_kernel<<<PB_TOT, 256, 0, stream>>>(ei32, ei64, flags, c1, s, prm, w1t, w2t, w3t);
  // 3-5) scan of c1 -> off1
  scanA_kernel<<<SBLK, 256, 0, stream>>>(c1, bsum);
  scanB_kernel<<<1, 256, 0, stream>>>(bsum, boff);
  scanC_kernel<<<SBLK, 256, 0, stream>>>(c1, boff, off1);

  const float *as1 = prm + H_POFF[1], *ad1 = prm + H_POFF[2], *b1 = prm + H_POFF[3];
  const float *as2 = prm + H_POFF[5], *ad2 = prm + H_POFF[6], *b2 = prm + H_POFF[7];
  const float *as3 = prm + H_POFF[9], *ad3 = prm + H_POFF[10], *b3 = prm + H_POFF[11];

  // 6) layer-1 GEMM(+al, direct-from-x) || coarse scatter into buckets
  gemm1_phaseC<<<GB1 + NCHK, 256, 0, stream>>>(
      d_in[0], flags, (const unsigned short*)w1t, h1, as1, ad1, als1, ald1,
      ei32, ei64, off1, tmp);
  // 7) per-bucket fine sort -> rowptr + ssrt
  phaseD_kernel<<<NB1, 256, 0, stream>>>(off1, tmp, rowptr, ssrt);
  // 8) aggregate L1 + layer-2 GEMM(+al), fused through LDS
  aggemm_kernel<128, 64><<<AB, 512, 0, stream>>>(
      rowptr, ssrt, als1, ald1, (const unsigned short*)h1, b1,
      (const unsigned short*)w2t, h2, as2, ad2, als2, ald2);
  // 9) aggregate L2 + layer-3 GEMM(+al), fused through LDS
  aggemm_kernel<64, 16><<<AB, 512, 0, stream>>>(
      rowptr, ssrt, als2, ald2, (const unsigned short*)h2, b2,
      (const unsigned short*)w3t, h3, as3, ad3, als3, ald3);
  // 10) aggregate L3 -> d_out (dtype per flags[1])
  agg_final<16><<<(N + 127) / 128, 256, 0, stream>>>(
      rowptr, ssrt, als3, ald3, (const unsigned short*)h3, b3, d_out, flags);
}